// Round 10
// baseline (267.687 us; speedup 1.0000x reference)
//
#include <hip/hip_runtime.h>
#include <math.h>

typedef short bf16x8 __attribute__((ext_vector_type(8)));
typedef short bf16x4 __attribute__((ext_vector_type(4)));
typedef float f32x4 __attribute__((ext_vector_type(4)));

#define MFMA_BF16(A,B,C) __builtin_amdgcn_mfma_f32_16x16x32_bf16(A,B,C,0,0,0)

#if __has_builtin(__builtin_amdgcn_mfma_f32_16x16x16bf16_1k)
#define HAVE_MFMA16 1
#define MFMA16(A,B,C) __builtin_amdgcn_mfma_f32_16x16x16bf16_1k(A,B,C,0,0,0)
#else
#define HAVE_MFMA16 0
#endif

__device__ __forceinline__ unsigned short f2b(float x) {
    union { float f; unsigned int u; } v; v.f = x;
    unsigned int r = v.u + 0x7FFFu + ((v.u >> 16) & 1u);
    return (unsigned short)(r >> 16);
}

// async global->LDS DMA, 16B per lane; LDS dest = wave-uniform base + lane*16
__device__ __forceinline__ void gload16(const unsigned short* g, unsigned short* l) {
    __builtin_amdgcn_global_load_lds(
        (const __attribute__((address_space(1))) unsigned int*)(g),
        (__attribute__((address_space(3))) unsigned int*)(l),
        16, 0, 0);
}
// 4B per lane variant; LDS dest = base + lane*4
__device__ __forceinline__ void gload4(const int* g, int* l) {
    __builtin_amdgcn_global_load_lds(
        (const __attribute__((address_space(1))) unsigned int*)(g),
        (__attribute__((address_space(3))) unsigned int*)(l),
        4, 0, 0);
}

// ---------------------------------------------------------------------------
// fp32 -> bf16 convert (flat)
// ---------------------------------------------------------------------------
__global__ __launch_bounds__(256) void conv_bf16(const float* __restrict__ s,
                                                 unsigned short* __restrict__ d, int n)
{
    int i = blockIdx.x * blockDim.x + threadIdx.x;
    int stride = gridDim.x * blockDim.x;
    for (int idx = i * 4; idx < n; idx += stride * 4) {
        float4 v = *(const float4*)(s + idx);
        ushort4 o;
        o.x = f2b(v.x); o.y = f2b(v.y); o.z = f2b(v.z); o.w = f2b(v.w);
        *(ushort4*)(d + idx) = o;
    }
}

// ---------------------------------------------------------------------------
// Fused weight transpose+convert: Wq|Wk|Wv (fp32, [2048][C]) -> bf16 [C][2048]
// ---------------------------------------------------------------------------
__global__ __launch_bounds__(256) void transp_conv_qkv(const float* __restrict__ Wq,
                                                       const float* __restrict__ Wk,
                                                       const float* __restrict__ Wv,
                                                       unsigned short* __restrict__ dst)
{
    __shared__ float t[32][33];
    const int tx = threadIdx.x, ty = threadIdx.y;   // (32,8)
    int bx = blockIdx.x;
    const float* src; int C, cb, dco;
    if (bx < 32)      { src = Wq; C = 1024; cb = bx;      dco = 0; }
    else if (bx < 40) { src = Wk; C = 256;  cb = bx - 32; dco = 1024; }
    else              { src = Wv; C = 256;  cb = bx - 40; dco = 1280; }
    const int c = cb * 32 + tx;
    const int r0 = blockIdx.y * 32;
#pragma unroll
    for (int i = 0; i < 4; ++i)
        t[ty + i * 8][tx] = src[(size_t)(r0 + ty + i * 8) * C + c];
    __syncthreads();
    const int cc = cb * 32 + ty;
#pragma unroll
    for (int i = 0; i < 4; ++i)
        dst[(size_t)(dco + cc + i * 8) * 2048 + r0 + tx] = f2b(t[tx][ty + i * 8]);
}

__global__ __launch_bounds__(256) void transp_conv(const float* __restrict__ src, int R, int C,
                                                   unsigned short* __restrict__ dst, int pitch)
{
    __shared__ float t[32][33];
    const int tx = threadIdx.x, ty = threadIdx.y;
    const int c = blockIdx.x * 32 + tx;
    const int r0 = blockIdx.y * 32;
#pragma unroll
    for (int i = 0; i < 4; ++i)
        t[ty + i * 8][tx] = src[(size_t)(r0 + ty + i * 8) * C + c];
    __syncthreads();
    const int cc = blockIdx.x * 32 + ty;
#pragma unroll
    for (int i = 0; i < 4; ++i)
        dst[(size_t)(cc + i * 8) * pitch + r0 + tx] = f2b(t[tx][ty + i * 8]);
}

// ---------------------------------------------------------------------------
// bf16 MFMA GEMM, B^T input: C[M][N] = A[M][K] @ Bt[N][K]^T
// BM=128, BN=64, BK=64; 256 threads (4 waves, 2x2); double-buffered
// global_load_lds staging; LDS as pitch-32 sub-tiles.  (unchanged from R7)
// ---------------------------------------------------------------------------
template <int MODE>
__global__ __launch_bounds__(256, 3) void gemm_bt_mfma(
    const unsigned short* __restrict__ A,
    const unsigned short* __restrict__ Bt,
    int M, int N, int K,
    float* __restrict__ Cf,
    unsigned short* __restrict__ qh,
    unsigned short* __restrict__ kh,
    unsigned short* __restrict__ vtt)
{
    __shared__ __align__(16) unsigned short As[2][2 * 128 * 32];
    __shared__ __align__(16) unsigned short Bs[2][2 * 64 * 32];

    const int tid = threadIdx.x;
    const int w = tid >> 6, lane = tid & 63, l15 = lane & 15, quad = lane >> 4;
    const int wm = w & 1, wn = w >> 1;
    const int m0 = blockIdx.y * 128, n0 = blockIdx.x * 64;

    f32x4 acc[4][2];
    const f32x4 zero4 = {0.f, 0.f, 0.f, 0.f};
#pragma unroll
    for (int i = 0; i < 4; ++i)
#pragma unroll
        for (int j = 0; j < 2; ++j) acc[i][j] = zero4;

    const int lrow = lane >> 2, lcol = (lane & 3) * 8;
    const unsigned short* AgL = A  + (size_t)(m0 + w * 32 + lrow) * K + lcol;
    const unsigned short* BgL = Bt + (size_t)(n0 + w * 16 + lrow) * K + lcol;

#pragma unroll
    for (int t = 0; t < 4; ++t) {
        const int sub = t >> 1, half = t & 1;
        gload16(AgL + (size_t)(half * 16) * K + sub * 32,
                &As[0][sub * 4096 + (w * 32 + half * 16) * 32]);
    }
#pragma unroll
    for (int kk = 0; kk < 2; ++kk)
        gload16(BgL + kk * 32, &Bs[0][kk * 2048 + (w * 16) * 32]);
    __syncthreads();

    int cb = 0;
    for (int k0 = 0; k0 < K; k0 += 64) {
        if (k0 + 64 < K) {
            const int nb = cb ^ 1;
#pragma unroll
            for (int t = 0; t < 4; ++t) {
                const int sub = t >> 1, half = t & 1;
                gload16(AgL + (size_t)(half * 16) * K + (k0 + 64) + sub * 32,
                        &As[nb][sub * 4096 + (w * 32 + half * 16) * 32]);
            }
#pragma unroll
            for (int kk = 0; kk < 2; ++kk)
                gload16(BgL + (k0 + 64) + kk * 32, &Bs[nb][kk * 2048 + (w * 16) * 32]);
        }

        bf16x8 af[4][2], bf[2][2];
#pragma unroll
        for (int kk = 0; kk < 2; ++kk) {
#pragma unroll
            for (int mt = 0; mt < 4; ++mt)
                af[mt][kk] = *(const bf16x8*)&As[cb][kk * 4096 + (wm * 64 + mt * 16 + l15) * 32 + quad * 8];
#pragma unroll
            for (int nt = 0; nt < 2; ++nt)
                bf[nt][kk] = *(const bf16x8*)&Bs[cb][kk * 2048 + (wn * 32 + nt * 16 + l15) * 32 + quad * 8];
        }
#pragma unroll
        for (int kk = 0; kk < 2; ++kk)
#pragma unroll
            for (int mt = 0; mt < 4; ++mt)
#pragma unroll
                for (int nt = 0; nt < 2; ++nt)
                    acc[mt][nt] = MFMA_BF16(af[mt][kk], bf[nt][kk], acc[mt][nt]);

        __syncthreads();
        cb ^= 1;
    }

    if (MODE == 0) {
#pragma unroll
        for (int mt = 0; mt < 4; ++mt)
#pragma unroll
            for (int nt = 0; nt < 2; ++nt) {
                const int gn = n0 + wn * 32 + nt * 16 + l15;
#pragma unroll
                for (int r = 0; r < 4; ++r) {
                    const int gm = m0 + wm * 64 + mt * 16 + quad * 4 + r;
                    Cf[(size_t)gm * N + gn] = acc[mt][nt][r];
                }
            }
    } else {
        if (n0 < 1024) {            // Q: tanh -> qh[m][n], pitch 1024
#pragma unroll
            for (int mt = 0; mt < 4; ++mt)
#pragma unroll
                for (int nt = 0; nt < 2; ++nt) {
                    const int gn = n0 + wn * 32 + nt * 16 + l15;
#pragma unroll
                    for (int r = 0; r < 4; ++r) {
                        const int gm = m0 + wm * 64 + mt * 16 + quad * 4 + r;
                        qh[(size_t)gm * 1024 + gn] = f2b(tanhf(acc[mt][nt][r]));
                    }
                }
        } else if (n0 < 1280) {     // K: tanh -> kh[m][n-1024], pitch 256
#pragma unroll
            for (int mt = 0; mt < 4; ++mt)
#pragma unroll
                for (int nt = 0; nt < 2; ++nt) {
                    const int gn = n0 + wn * 32 + nt * 16 + l15 - 1024;
#pragma unroll
                    for (int r = 0; r < 4; ++r) {
                        const int gm = m0 + wm * 64 + mt * 16 + quad * 4 + r;
                        kh[(size_t)gm * 256 + gn] = f2b(tanhf(acc[mt][nt][r]));
                    }
                }
        } else {                    // V: sigmoid -> vtt[(b*4+g)*64+v][s]
#pragma unroll
            for (int mt = 0; mt < 4; ++mt)
#pragma unroll
                for (int nt = 0; nt < 2; ++nt) {
                    const int gn = n0 + wn * 32 + nt * 16 + l15 - 1280;
                    const int g = gn >> 6, vv = gn & 63;
                    const int s0 = m0 + wm * 64 + mt * 16 + quad * 4;
                    const int b = s0 >> 11, sl = s0 & 2047;
                    ushort4 pk;
                    unsigned short* pp = (unsigned short*)&pk;
#pragma unroll
                    for (int r = 0; r < 4; ++r) {
                        float sv = 1.0f / (1.0f + __expf(-acc[mt][nt][r]));
                        pp[r] = f2b(sv);
                    }
                    *(ushort4*)&vtt[((size_t)(b * 4 + g) * 64 + vv) * 2048 + sl] = pk;
                }
        }
    }
}

// ---------------------------------------------------------------------------
// MFMA flash attention: paired q-tiles (uniform 33 k-tiles/block), DMA-staged
// double-buffered K/V, fixed-max softmax.
// NEW (R10): PV uses 16x16x16 MFMA with the A-fragment built DIRECTLY from
// the S^T C-layout registers (S^T lane layout [j=quad*4+r][q=l15] == A-operand
// layout [m=l15][k=quad*4+i]) -> no P LDS round-trip at all.
// ---------------------------------------------------------------------------
__global__ __launch_bounds__(256) void rosa_attn_mfma(
    const unsigned short* __restrict__ qh,
    const unsigned short* __restrict__ kh,
    const unsigned short* __restrict__ vtt,
    const int* __restrict__ amask,
    const float* __restrict__ emb0,
    const float* __restrict__ emb1,
    unsigned short* __restrict__ ob)
{
    __shared__ __align__(16) unsigned short Ks[2][2][64 * 32];  // [buf][kk][row*32+c]
    __shared__ __align__(16) unsigned short Vs[2][2][64 * 32];  // [buf][kk][v*32+j]
#if !HAVE_MFMA16
    __shared__ __align__(16) unsigned short Ps[4][16][72];      // fallback only
#endif
    __shared__ int Mski[2][64];

    const int pairI = blockIdx.x;                 // 0..15
    const int h = blockIdx.y, b = blockIdx.z, g = h >> 2;
    const int tid = threadIdx.x;
    const int w = tid >> 6, lane = tid & 63, l15 = lane & 15, quad = lane >> 4;

    // DMA lane geometry: row = lane>>2 (16 rows/issue), col = (lane&3)*8
    const int lrow = lane >> 2, lcol = (lane & 3) * 8;
    const unsigned short* kst = kh + (size_t)b * 2048 * 256 + g * 64
                               + (size_t)(w * 16 + lrow) * 256 + lcol;   // + k0*256 + kk*32
    const unsigned short* vst = vtt + ((size_t)(b * 4 + g) * 64) * 2048
                               + (size_t)(w * 16 + lrow) * 2048 + lcol;  // + k0 + kk*32
    const int* mbase = amask + b * 2048;

    const f32x4 zero4 = {0.f, 0.f, 0.f, 0.f};
    const float cexp = 0.0225421100f;             // log2(e)/64

#define STAGE_TILE(k0s, buf)                                              \
    {                                                                     \
        gload16(kst + (size_t)(k0s) * 256,      &Ks[buf][0][(w * 16) * 32]); \
        gload16(kst + (size_t)(k0s) * 256 + 32, &Ks[buf][1][(w * 16) * 32]); \
        gload16(vst + (k0s),                    &Vs[buf][0][(w * 16) * 32]); \
        gload16(vst + (k0s) + 32,               &Vs[buf][1][(w * 16) * 32]); \
        if (w == 0) gload4(mbase + (k0s) + lane, &Mski[buf][0]);          \
    }

    for (int half = 0; half < 2; ++half) {
        const int qt = (half == 0) ? pairI : 31 - pairI;
        const int q0 = qt * 64;
        const int nkt = qt + 1;
        const int qg = q0 + w * 16 + l15;

        // Q B-fragment (n = q = l15, k = d), per wave, from global (L2-hot)
        const unsigned short* qrow = qh + ((size_t)(b * 2048 + q0 + w * 16 + l15) * 16 + h) * 64;
        const bf16x8 qf0 = *(const bf16x8*)(qrow + quad * 8);
        const bf16x8 qf1 = *(const bf16x8*)(qrow + 32 + quad * 8);

        f32x4 oacc[4];
#pragma unroll
        for (int t = 0; t < 4; ++t) oacc[t] = zero4;
        float psum = 0.0f;

        __syncthreads();           // protect bufs from previous half's readers
        STAGE_TILE(0, 0)
        __syncthreads();           // vmcnt(0) drain: tile 0 visible

        int cb = 0;
        for (int kt = 0; kt < nkt; ++kt) {
            if (kt + 1 < nkt) STAGE_TILE((kt + 1) * 64, cb ^ 1)

            const int k0 = kt * 64;
            const bool diag = (kt == qt);
            const int ntlim = diag ? (w + 1) : 4;

#if HAVE_MFMA16
            // S^T = K.Q^T per 16-j window; softmax; A-frag built in registers
            bf16x4 pfrag[4];
#pragma unroll
            for (int jw = 0; jw < 4; ++jw) {
                if (jw < ntlim) {
                    bf16x8 kf0 = *(const bf16x8*)&Ks[cb][0][(jw * 16 + l15) * 32 + quad * 8];
                    bf16x8 kf1 = *(const bf16x8*)&Ks[cb][1][(jw * 16 + l15) * 32 + quad * 8];
                    f32x4 sc = MFMA_BF16(kf0, qf0, zero4);
                    sc = MFMA_BF16(kf1, qf1, sc);
                    const int4 m4 = *(const int4*)&Mski[cb][jw * 16 + quad * 4];
                    const int* mm = (const int*)&m4;
                    short* pp = (short*)&pfrag[jw];
#pragma unroll
                    for (int r = 0; r < 4; ++r) {
                        float p = __builtin_exp2f(sc[r] * cexp);
                        bool valid = (mm[r] != 0);
                        if (diag) valid = valid && ((k0 + jw * 16 + quad * 4 + r) <= qg);
                        p = valid ? p : 0.0f;
                        psum += p;
                        pp[r] = (short)f2b(p);
                    }
                }
            }

            // O += P.V : oacc[nt] += MFMA16(pfrag[jw], V[jw-window][nt-window])
#pragma unroll
            for (int jw = 0; jw < 4; ++jw) {
                if (jw < ntlim) {
#pragma unroll
                    for (int nt = 0; nt < 4; ++nt) {
                        bf16x4 vf = *(const bf16x4*)&Vs[cb][jw >> 1]
                            [(nt * 16 + l15) * 32 + (jw & 1) * 16 + quad * 4];
                        oacc[nt] = MFMA16(pfrag[jw], vf, oacc[nt]);
                    }
                }
            }
#else
            // fallback: R9 path via Ps LDS round-trip
#pragma unroll
            for (int nt = 0; nt < 4; ++nt) {
                ushort4 pk;
                if (nt < ntlim) {
                    bf16x8 kf0 = *(const bf16x8*)&Ks[cb][0][(nt * 16 + l15) * 32 + quad * 8];
                    bf16x8 kf1 = *(const bf16x8*)&Ks[cb][1][(nt * 16 + l15) * 32 + quad * 8];
                    f32x4 sc = MFMA_BF16(kf0, qf0, zero4);
                    sc = MFMA_BF16(kf1, qf1, sc);
                    const int4 m4 = *(const int4*)&Mski[cb][nt * 16 + quad * 4];
                    const int* mm = (const int*)&m4;
                    unsigned short* pp = (unsigned short*)&pk;
#pragma unroll
                    for (int r = 0; r < 4; ++r) {
                        float p = __builtin_exp2f(sc[r] * cexp);
                        bool valid = (mm[r] != 0);
                        if (diag) valid = valid && ((k0 + nt * 16 + quad * 4 + r) <= qg);
                        p = valid ? p : 0.0f;
                        psum += p;
                        pp[r] = f2b(p);
                    }
                } else {
                    pk.x = 0; pk.y = 0; pk.z = 0; pk.w = 0;
                }
                *(ushort4*)&Ps[w][l15][nt * 16 + quad * 4] = pk;
            }
            const bf16x8 pf0 = *(const bf16x8*)&Ps[w][l15][quad * 8];
            const bf16x8 pf1 = *(const bf16x8*)&Ps[w][l15][32 + quad * 8];
#pragma unroll
            for (int nt = 0; nt < 4; ++nt) {
                bf16x8 vf0 = *(const bf16x8*)&Vs[cb][0][(nt * 16 + l15) * 32 + quad * 8];
                bf16x8 vf1 = *(const bf16x8*)&Vs[cb][1][(nt * 16 + l15) * 32 + quad * 8];
                oacc[nt] = MFMA_BF16(pf0, vf0, oacc[nt]);
                oacc[nt] = MFMA_BF16(pf1, vf1, oacc[nt]);
            }
#endif

            if (kt + 1 < nkt) {
                __syncthreads();   // drains next tile's DMA + all waves' cb reads
                cb ^= 1;
            }
        }

        // l reduction: sum partials across the 4 quads holding the same q
        float l = psum;
        l += __shfl_xor(l, 16);
        l += __shfl_xor(l, 32);
        float lq[4];
#pragma unroll
        for (int r = 0; r < 4; ++r) lq[r] = __shfl(l, quad * 4 + r);

        // epilogue: oacc row = q_local = quad*4+r, col = v = nt*16+l15
#pragma unroll
        for (int nt = 0; nt < 4; ++nt) {
            const float e0 = emb0[h * 64 + nt * 16 + l15];
            const float e1 = emb1[h * 64 + nt * 16 + l15];
#pragma unroll
            for (int r = 0; r < 4; ++r) {
                const float ctx = oacc[nt][r] / lq[r];
                const float val = e0 + ctx * (e1 - e0);
                const size_t s_idx = (size_t)(b * 2048 + q0 + w * 16 + quad * 4 + r);
                ob[(s_idx * 16 + h) * 64 + nt * 16 + l15] = f2b(val);
            }
        }
    }
#undef STAGE_TILE
}

// ---------------------------------------------------------------------------
extern "C" void kernel_launch(void* const* d_in, const int* in_sizes, int n_in,
                              void* d_out, int out_size, void* d_ws, size_t ws_size,
                              hipStream_t stream)
{
    const float* x    = (const float*)d_in[0];
    const int*   amask= (const int*)d_in[1];
    const float* Wq   = (const float*)d_in[2];
    const float* Wk   = (const float*)d_in[3];
    const float* Wv   = (const float*)d_in[4];
    const float* Wo   = (const float*)d_in[5];
    const float* emb0 = (const float*)d_in[6];
    const float* emb1 = (const float*)d_in[7];
    float* out = (float*)d_out;

    char* base = (char*)d_ws;
    unsigned short* xh    = (unsigned short*)(base);                      // 16 MB
    unsigned short* ob    = xh;                                           // aliases xh
    unsigned short* Wqkvt = (unsigned short*)(base + (16u << 20));        // 6 MB
    unsigned short* Wot   = (unsigned short*)(base + (22u << 20));        // 4 MB
    unsigned short* qh    = (unsigned short*)(base + (26u << 20));        // 8 MB
    unsigned short* kh    = (unsigned short*)(base + (34u << 20));        // 2 MB
    unsigned short* vtt   = (unsigned short*)(base + (36u << 20));        // 2 MB

    conv_bf16<<<2048, 256, 0, stream>>>(x, xh, 4096 * 2048);
    transp_conv_qkv<<<dim3(48, 64), dim3(32, 8), 0, stream>>>(Wq, Wk, Wv, Wqkvt);
    transp_conv<<<dim3(64, 32), dim3(32, 8), 0, stream>>>(Wo, 1024, 2048, Wot, 1024);

    gemm_bt_mfma<1><<<dim3(24, 32), 256, 0, stream>>>(xh, Wqkvt, 4096, 1536, 2048,
                                                      nullptr, qh, kh, vtt);
    rosa_attn_mfma<<<dim3(16, 16, 2), 256, 0, stream>>>(qh, kh, vtt, amask, emb0, emb1, ob);
    gemm_bt_mfma<0><<<dim3(32, 32), 256, 0, stream>>>(ob, Wot, 4096, 2048, 1024,
                                                      out, nullptr, nullptr, nullptr);
}

// Round 12
// 239.366 us; speedup vs baseline: 1.1183x; 1.1183x over previous
//
#include <hip/hip_runtime.h>
#include <math.h>

typedef short bf16x8 __attribute__((ext_vector_type(8)));
typedef float f32x4 __attribute__((ext_vector_type(4)));

#define MFMA_BF16(A,B,C) __builtin_amdgcn_mfma_f32_16x16x32_bf16(A,B,C,0,0,0)

__device__ __forceinline__ unsigned short f2b(float x) {
    union { float f; unsigned int u; } v; v.f = x;
    unsigned int r = v.u + 0x7FFFu + ((v.u >> 16) & 1u);
    return (unsigned short)(r >> 16);
}

// async global->LDS DMA, 16B per lane; LDS dest = wave-uniform base + lane*16
__device__ __forceinline__ void gload16(const unsigned short* g, unsigned short* l) {
    __builtin_amdgcn_global_load_lds(
        (const __attribute__((address_space(1))) unsigned int*)(g),
        (__attribute__((address_space(3))) unsigned int*)(l),
        16, 0, 0);
}
// 4B per lane variant; LDS dest = base + lane*4
__device__ __forceinline__ void gload4(const int* g, int* l) {
    __builtin_amdgcn_global_load_lds(
        (const __attribute__((address_space(1))) unsigned int*)(g),
        (__attribute__((address_space(3))) unsigned int*)(l),
        4, 0, 0);
}

// ---------------------------------------------------------------------------
// fp32 -> bf16 convert (flat)
// ---------------------------------------------------------------------------
__global__ __launch_bounds__(256) void conv_bf16(const float* __restrict__ s,
                                                 unsigned short* __restrict__ d, int n)
{
    int i = blockIdx.x * blockDim.x + threadIdx.x;
    int stride = gridDim.x * blockDim.x;
    for (int idx = i * 4; idx < n; idx += stride * 4) {
        float4 v = *(const float4*)(s + idx);
        ushort4 o;
        o.x = f2b(v.x); o.y = f2b(v.y); o.z = f2b(v.z); o.w = f2b(v.w);
        *(ushort4*)(d + idx) = o;
    }
}

// ---------------------------------------------------------------------------
// Fused weight transpose+convert: Wq|Wk|Wv (fp32, [2048][C]) -> bf16 [C][2048]
// ---------------------------------------------------------------------------
__global__ __launch_bounds__(256) void transp_conv_qkv(const float* __restrict__ Wq,
                                                       const float* __restrict__ Wk,
                                                       const float* __restrict__ Wv,
                                                       unsigned short* __restrict__ dst)
{
    __shared__ float t[32][33];
    const int tx = threadIdx.x, ty = threadIdx.y;   // (32,8)
    int bx = blockIdx.x;
    const float* src; int C, cb, dco;
    if (bx < 32)      { src = Wq; C = 1024; cb = bx;      dco = 0; }
    else if (bx < 40) { src = Wk; C = 256;  cb = bx - 32; dco = 1024; }
    else              { src = Wv; C = 256;  cb = bx - 40; dco = 1280; }
    const int c = cb * 32 + tx;
    const int r0 = blockIdx.y * 32;
#pragma unroll
    for (int i = 0; i < 4; ++i)
        t[ty + i * 8][tx] = src[(size_t)(r0 + ty + i * 8) * C + c];
    __syncthreads();
    const int cc = cb * 32 + ty;
#pragma unroll
    for (int i = 0; i < 4; ++i)
        dst[(size_t)(dco + cc + i * 8) * 2048 + r0 + tx] = f2b(t[tx][ty + i * 8]);
}

__global__ __launch_bounds__(256) void transp_conv(const float* __restrict__ src, int R, int C,
                                                   unsigned short* __restrict__ dst, int pitch)
{
    __shared__ float t[32][33];
    const int tx = threadIdx.x, ty = threadIdx.y;
    const int c = blockIdx.x * 32 + tx;
    const int r0 = blockIdx.y * 32;
#pragma unroll
    for (int i = 0; i < 4; ++i)
        t[ty + i * 8][tx] = src[(size_t)(r0 + ty + i * 8) * C + c];
    __syncthreads();
    const int cc = blockIdx.x * 32 + ty;
#pragma unroll
    for (int i = 0; i < 4; ++i)
        dst[(size_t)(cc + i * 8) * pitch + r0 + tx] = f2b(t[tx][ty + i * 8]);
}

// ---------------------------------------------------------------------------
// bf16 MFMA GEMM, B^T input: C[M][N] = A[M][K] @ Bt[N][K]^T
// BM=128, BN=64, BK=64; 256 threads (4 waves, 2x2); double-buffered
// global_load_lds staging; LDS as pitch-32 sub-tiles.  (unchanged from R7)
// ---------------------------------------------------------------------------
template <int MODE>
__global__ __launch_bounds__(256, 3) void gemm_bt_mfma(
    const unsigned short* __restrict__ A,
    const unsigned short* __restrict__ Bt,
    int M, int N, int K,
    float* __restrict__ Cf,
    unsigned short* __restrict__ qh,
    unsigned short* __restrict__ kh,
    unsigned short* __restrict__ vtt)
{
    __shared__ __align__(16) unsigned short As[2][2 * 128 * 32];
    __shared__ __align__(16) unsigned short Bs[2][2 * 64 * 32];

    const int tid = threadIdx.x;
    const int w = tid >> 6, lane = tid & 63, l15 = lane & 15, quad = lane >> 4;
    const int wm = w & 1, wn = w >> 1;
    const int m0 = blockIdx.y * 128, n0 = blockIdx.x * 64;

    f32x4 acc[4][2];
    const f32x4 zero4 = {0.f, 0.f, 0.f, 0.f};
#pragma unroll
    for (int i = 0; i < 4; ++i)
#pragma unroll
        for (int j = 0; j < 2; ++j) acc[i][j] = zero4;

    const int lrow = lane >> 2, lcol = (lane & 3) * 8;
    const unsigned short* AgL = A  + (size_t)(m0 + w * 32 + lrow) * K + lcol;
    const unsigned short* BgL = Bt + (size_t)(n0 + w * 16 + lrow) * K + lcol;

#pragma unroll
    for (int t = 0; t < 4; ++t) {
        const int sub = t >> 1, half = t & 1;
        gload16(AgL + (size_t)(half * 16) * K + sub * 32,
                &As[0][sub * 4096 + (w * 32 + half * 16) * 32]);
    }
#pragma unroll
    for (int kk = 0; kk < 2; ++kk)
        gload16(BgL + kk * 32, &Bs[0][kk * 2048 + (w * 16) * 32]);
    __syncthreads();

    int cb = 0;
    for (int k0 = 0; k0 < K; k0 += 64) {
        if (k0 + 64 < K) {
            const int nb = cb ^ 1;
#pragma unroll
            for (int t = 0; t < 4; ++t) {
                const int sub = t >> 1, half = t & 1;
                gload16(AgL + (size_t)(half * 16) * K + (k0 + 64) + sub * 32,
                        &As[nb][sub * 4096 + (w * 32 + half * 16) * 32]);
            }
#pragma unroll
            for (int kk = 0; kk < 2; ++kk)
                gload16(BgL + (k0 + 64) + kk * 32, &Bs[nb][kk * 2048 + (w * 16) * 32]);
        }

        bf16x8 af[4][2], bf[2][2];
#pragma unroll
        for (int kk = 0; kk < 2; ++kk) {
#pragma unroll
            for (int mt = 0; mt < 4; ++mt)
                af[mt][kk] = *(const bf16x8*)&As[cb][kk * 4096 + (wm * 64 + mt * 16 + l15) * 32 + quad * 8];
#pragma unroll
            for (int nt = 0; nt < 2; ++nt)
                bf[nt][kk] = *(const bf16x8*)&Bs[cb][kk * 2048 + (wn * 32 + nt * 16 + l15) * 32 + quad * 8];
        }
#pragma unroll
        for (int kk = 0; kk < 2; ++kk)
#pragma unroll
            for (int mt = 0; mt < 4; ++mt)
#pragma unroll
                for (int nt = 0; nt < 2; ++nt)
                    acc[mt][nt] = MFMA_BF16(af[mt][kk], bf[nt][kk], acc[mt][nt]);

        __syncthreads();
        cb ^= 1;
    }

    if (MODE == 0) {
#pragma unroll
        for (int mt = 0; mt < 4; ++mt)
#pragma unroll
            for (int nt = 0; nt < 2; ++nt) {
                const int gn = n0 + wn * 32 + nt * 16 + l15;
#pragma unroll
                for (int r = 0; r < 4; ++r) {
                    const int gm = m0 + wm * 64 + mt * 16 + quad * 4 + r;
                    Cf[(size_t)gm * N + gn] = acc[mt][nt][r];
                }
            }
    } else {
        if (n0 < 1024) {            // Q: tanh -> qh[m][n], pitch 1024
#pragma unroll
            for (int mt = 0; mt < 4; ++mt)
#pragma unroll
                for (int nt = 0; nt < 2; ++nt) {
                    const int gn = n0 + wn * 32 + nt * 16 + l15;
#pragma unroll
                    for (int r = 0; r < 4; ++r) {
                        const int gm = m0 + wm * 64 + mt * 16 + quad * 4 + r;
                        qh[(size_t)gm * 1024 + gn] = f2b(tanhf(acc[mt][nt][r]));
                    }
                }
        } else if (n0 < 1280) {     // K: tanh -> kh[m][n-1024], pitch 256
#pragma unroll
            for (int mt = 0; mt < 4; ++mt)
#pragma unroll
                for (int nt = 0; nt < 2; ++nt) {
                    const int gn = n0 + wn * 32 + nt * 16 + l15 - 1024;
#pragma unroll
                    for (int r = 0; r < 4; ++r) {
                        const int gm = m0 + wm * 64 + mt * 16 + quad * 4 + r;
                        kh[(size_t)gm * 256 + gn] = f2b(tanhf(acc[mt][nt][r]));
                    }
                }
        } else {                    // V: sigmoid -> vtt[(b*4+g)*64+v][s]
#pragma unroll
            for (int mt = 0; mt < 4; ++mt)
#pragma unroll
                for (int nt = 0; nt < 2; ++nt) {
                    const int gn = n0 + wn * 32 + nt * 16 + l15 - 1280;
                    const int g = gn >> 6, vv = gn & 63;
                    const int s0 = m0 + wm * 64 + mt * 16 + quad * 4;
                    const int b = s0 >> 11, sl = s0 & 2047;
                    ushort4 pk;
                    unsigned short* pp = (unsigned short*)&pk;
#pragma unroll
                    for (int r = 0; r < 4; ++r) {
                        float sv = 1.0f / (1.0f + __expf(-acc[mt][nt][r]));
                        pp[r] = f2b(sv);
                    }
                    *(ushort4*)&vtt[((size_t)(b * 4 + g) * 64 + vv) * 2048 + sl] = pk;
                }
        }
    }
}

// ---------------------------------------------------------------------------
// MFMA flash attention, R11: JOINT-PAIR k-loop. Block = (pairI, h, b) handles
// q-tiles qt0=pairI and qt1=31-pairI in ONE loop kt=0..qt1 (half0 active
// while kt<=qt0). K/V staged once per kt (was twice for kt<=qt0); K/V
// fragment b128 reads shared by both halves; two independent QK/PV chains
// per barrier interval (ILP). Fixed-max softmax; Ps LDS round-trip per half
// (R9's proven b128 geometry — R10's b64 path was an 8-way bank conflict).
// ---------------------------------------------------------------------------
__global__ __launch_bounds__(256) void rosa_attn_mfma(
    const unsigned short* __restrict__ qh,
    const unsigned short* __restrict__ kh,
    const unsigned short* __restrict__ vtt,
    const int* __restrict__ amask,
    const float* __restrict__ emb0,
    const float* __restrict__ emb1,
    unsigned short* __restrict__ ob)
{
    __shared__ __align__(16) unsigned short Ks[2][2][64 * 32];  // [buf][kk][row*32+c]
    __shared__ __align__(16) unsigned short Vs[2][2][64 * 32];  // [buf][kk][v*32+j]
    __shared__ __align__(16) unsigned short Ps[4][2][16][72];   // [wave][half][q][j]
    __shared__ int Mski[2][64];

    const int pairI = blockIdx.x;                 // 0..15
    const int h = blockIdx.y, b = blockIdx.z, g = h >> 2;
    const int tid = threadIdx.x;
    const int w = tid >> 6, lane = tid & 63, l15 = lane & 15, quad = lane >> 4;

    const int qt0 = pairI, qt1 = 31 - pairI;      // qt1 > qt0 always
    const int q00 = qt0 * 64, q01 = qt1 * 64;
    const int qg0 = q00 + w * 16 + l15;
    const int qg1 = q01 + w * 16 + l15;

    // DMA lane geometry: row = lane>>2 (16 rows/issue), col = (lane&3)*8
    const int lrow = lane >> 2, lcol = (lane & 3) * 8;
    const unsigned short* kst = kh + (size_t)b * 2048 * 256 + g * 64
                               + (size_t)(w * 16 + lrow) * 256 + lcol;   // + k0*256 + kk*32
    const unsigned short* vst = vtt + ((size_t)(b * 4 + g) * 64) * 2048
                               + (size_t)(w * 16 + lrow) * 2048 + lcol;  // + k0 + kk*32
    const int* mbase = amask + b * 2048;

    const f32x4 zero4 = {0.f, 0.f, 0.f, 0.f};
    const float cexp = 0.0225421100f;             // log2(e)/64

    // Q B-fragments for both halves (n = q = l15, k = d), from global (L2-hot)
    const unsigned short* qrow0 = qh + ((size_t)(b * 2048 + q00 + w * 16 + l15) * 16 + h) * 64;
    const unsigned short* qrow1 = qh + ((size_t)(b * 2048 + q01 + w * 16 + l15) * 16 + h) * 64;
    const bf16x8 qf00 = *(const bf16x8*)(qrow0 + quad * 8);
    const bf16x8 qf01 = *(const bf16x8*)(qrow0 + 32 + quad * 8);
    const bf16x8 qf10 = *(const bf16x8*)(qrow1 + quad * 8);
    const bf16x8 qf11 = *(const bf16x8*)(qrow1 + 32 + quad * 8);

    f32x4 oacc0[4], oacc1[4];
#pragma unroll
    for (int t = 0; t < 4; ++t) { oacc0[t] = zero4; oacc1[t] = zero4; }
    float psum0 = 0.0f, psum1 = 0.0f;

#define STAGE_TILE(k0s, buf)                                              \
    {                                                                     \
        gload16(kst + (size_t)(k0s) * 256,      &Ks[buf][0][(w * 16) * 32]); \
        gload16(kst + (size_t)(k0s) * 256 + 32, &Ks[buf][1][(w * 16) * 32]); \
        gload16(vst + (k0s),                    &Vs[buf][0][(w * 16) * 32]); \
        gload16(vst + (k0s) + 32,               &Vs[buf][1][(w * 16) * 32]); \
        if (w == 0) gload4(mbase + (k0s) + lane, &Mski[buf][0]);          \
    }

    STAGE_TILE(0, 0)
    __syncthreads();                              // vmcnt(0) drain: tile 0 visible

    int cb = 0;
    const int nkt = qt1 + 1;
    for (int kt = 0; kt < nkt; ++kt) {
        if (kt + 1 < nkt) STAGE_TILE((kt + 1) * 64, cb ^ 1)

        const int k0 = kt * 64;

        // shared K/V fragments (used by both halves)
        bf16x8 kf[4][2], vf[4][2];
#pragma unroll
        for (int nt = 0; nt < 4; ++nt) {
            kf[nt][0] = *(const bf16x8*)&Ks[cb][0][(nt * 16 + l15) * 32 + quad * 8];
            kf[nt][1] = *(const bf16x8*)&Ks[cb][1][(nt * 16 + l15) * 32 + quad * 8];
            vf[nt][0] = *(const bf16x8*)&Vs[cb][0][(nt * 16 + l15) * 32 + quad * 8];
            vf[nt][1] = *(const bf16x8*)&Vs[cb][1][(nt * 16 + l15) * 32 + quad * 8];
        }

        // ---- half 0 (active while kt <= qt0) ----
        if (kt <= qt0) {
            const bool diag = (kt == qt0);
            const int ntlim = diag ? (w + 1) : 4;
#pragma unroll
            for (int nt = 0; nt < 4; ++nt) {
                ushort4 pk;
                if (nt < ntlim) {
                    f32x4 sc = MFMA_BF16(kf[nt][0], qf00, zero4);
                    sc = MFMA_BF16(kf[nt][1], qf01, sc);
                    const int4 m4 = *(const int4*)&Mski[cb][nt * 16 + quad * 4];
                    const int* mm = (const int*)&m4;
                    unsigned short* pp = (unsigned short*)&pk;
#pragma unroll
                    for (int r = 0; r < 4; ++r) {
                        float p = __builtin_exp2f(sc[r] * cexp);
                        bool valid = (mm[r] != 0);
                        if (diag) valid = valid && ((k0 + nt * 16 + quad * 4 + r) <= qg0);
                        p = valid ? p : 0.0f;
                        psum0 += p;
                        pp[r] = f2b(p);
                    }
                } else {
                    pk.x = 0; pk.y = 0; pk.z = 0; pk.w = 0;
                }
                *(ushort4*)&Ps[w][0][l15][nt * 16 + quad * 4] = pk;
            }
            const bf16x8 pf0 = *(const bf16x8*)&Ps[w][0][l15][quad * 8];
            const bf16x8 pf1 = *(const bf16x8*)&Ps[w][0][l15][32 + quad * 8];
#pragma unroll
            for (int nt = 0; nt < 4; ++nt) {
                oacc0[nt] = MFMA_BF16(pf0, vf[nt][0], oacc0[nt]);
                oacc0[nt] = MFMA_BF16(pf1, vf[nt][1], oacc0[nt]);
            }
        }

        // ---- half 1 (always active; kt <= qt1 by loop bound) ----
        {
            const bool diag = (kt == qt1);
            const int ntlim = diag ? (w + 1) : 4;
#pragma unroll
            for (int nt = 0; nt < 4; ++nt) {
                ushort4 pk;
                if (nt < ntlim) {
                    f32x4 sc = MFMA_BF16(kf[nt][0], qf10, zero4);
                    sc = MFMA_BF16(kf[nt][1], qf11, sc);
                    const int4 m4 = *(const int4*)&Mski[cb][nt * 16 + quad * 4];
                    const int* mm = (const int*)&m4;
                    unsigned short* pp = (unsigned short*)&pk;
#pragma unroll
                    for (int r = 0; r < 4; ++r) {
                        float p = __builtin_exp2f(sc[r] * cexp);
                        bool valid = (mm[r] != 0);
                        if (diag) valid = valid && ((k0 + nt * 16 + quad * 4 + r) <= qg1);
                        p = valid ? p : 0.0f;
                        psum1 += p;
                        pp[r] = f2b(p);
                    }
                } else {
                    pk.x = 0; pk.y = 0; pk.z = 0; pk.w = 0;
                }
                *(ushort4*)&Ps[w][1][l15][nt * 16 + quad * 4] = pk;
            }
            const bf16x8 pf0 = *(const bf16x8*)&Ps[w][1][l15][quad * 8];
            const bf16x8 pf1 = *(const bf16x8*)&Ps[w][1][l15][32 + quad * 8];
#pragma unroll
            for (int nt = 0; nt < 4; ++nt) {
                oacc1[nt] = MFMA_BF16(pf0, vf[nt][0], oacc1[nt]);
                oacc1[nt] = MFMA_BF16(pf1, vf[nt][1], oacc1[nt]);
            }
        }

        if (kt + 1 < nkt) {
            __syncthreads();   // drains next tile's DMA + all waves' cb reads
            cb ^= 1;
        }
    }
#undef STAGE_TILE

    // ---- epilogues (both halves) ----
#pragma unroll
    for (int half = 0; half < 2; ++half) {
        const float psum = half ? psum1 : psum0;
        const int q0 = half ? q01 : q00;
        f32x4* oacc = half ? oacc1 : oacc0;

        float l = psum;
        l += __shfl_xor(l, 16);
        l += __shfl_xor(l, 32);
        float lq[4];
#pragma unroll
        for (int r = 0; r < 4; ++r) lq[r] = __shfl(l, quad * 4 + r);

#pragma unroll
        for (int nt = 0; nt < 4; ++nt) {
            const float e0 = emb0[h * 64 + nt * 16 + l15];
            const float e1 = emb1[h * 64 + nt * 16 + l15];
#pragma unroll
            for (int r = 0; r < 4; ++r) {
                const float ctx = oacc[nt][r] / lq[r];
                const float val = e0 + ctx * (e1 - e0);
                const size_t s_idx = (size_t)(b * 2048 + q0 + w * 16 + quad * 4 + r);
                ob[(s_idx * 16 + h) * 64 + nt * 16 + l15] = f2b(val);
            }
        }
    }
}

// ---------------------------------------------------------------------------
extern "C" void kernel_launch(void* const* d_in, const int* in_sizes, int n_in,
                              void* d_out, int out_size, void* d_ws, size_t ws_size,
                              hipStream_t stream)
{
    const float* x    = (const float*)d_in[0];
    const int*   amask= (const int*)d_in[1];
    const float* Wq   = (const float*)d_in[2];
    const float* Wk   = (const float*)d_in[3];
    const float* Wv   = (const float*)d_in[4];
    const float* Wo   = (const float*)d_in[5];
    const float* emb0 = (const float*)d_in[6];
    const float* emb1 = (const float*)d_in[7];
    float* out = (float*)d_out;

    char* base = (char*)d_ws;
    unsigned short* xh    = (unsigned short*)(base);                      // 16 MB
    unsigned short* ob    = xh;                                           // aliases xh
    unsigned short* Wqkvt = (unsigned short*)(base + (16u << 20));        // 6 MB
    unsigned short* Wot   = (unsigned short*)(base + (22u << 20));        // 4 MB
    unsigned short* qh    = (unsigned short*)(base + (26u << 20));        // 8 MB
    unsigned short* kh    = (unsigned short*)(base + (34u << 20));        // 2 MB
    unsigned short* vtt   = (unsigned short*)(base + (36u << 20));        // 2 MB

    conv_bf16<<<2048, 256, 0, stream>>>(x, xh, 4096 * 2048);
    transp_conv_qkv<<<dim3(48, 64), dim3(32, 8), 0, stream>>>(Wq, Wk, Wv, Wqkvt);
    transp_conv<<<dim3(64, 32), dim3(32, 8), 0, stream>>>(Wo, 1024, 2048, Wot, 1024);

    gemm_bt_mfma<1><<<dim3(24, 32), 256, 0, stream>>>(xh, Wqkvt, 4096, 1536, 2048,
                                                      nullptr, qh, kh, vtt);
    rosa_attn_mfma<<<dim3(16, 16, 2), 256, 0, stream>>>(qh, kh, vtt, amask, emb0, emb1, ob);
    gemm_bt_mfma<0><<<dim3(32, 32), 256, 0, stream>>>(ob, Wot, 4096, 2048, 1024,
                                                      out, nullptr, nullptr, nullptr);
}

// Round 13
// 236.500 us; speedup vs baseline: 1.1319x; 1.0121x over previous
//
#include <hip/hip_runtime.h>
#include <math.h>

typedef short bf16x8 __attribute__((ext_vector_type(8)));
typedef short bf16x2 __attribute__((ext_vector_type(2)));
typedef float f32x4 __attribute__((ext_vector_type(4)));

#define MFMA_BF16(A,B,C) __builtin_amdgcn_mfma_f32_16x16x32_bf16(A,B,C,0,0,0)

__device__ __forceinline__ unsigned short f2b(float x) {
    union { float f; unsigned int u; } v; v.f = x;
    unsigned int r = v.u + 0x7FFFu + ((v.u >> 16) & 1u);
    return (unsigned short)(r >> 16);
}

// packed f32x2 -> bf16x2 (RNE); hardware v_cvt_pk_bf16_f32 when available
#if __has_builtin(__builtin_amdgcn_cvt_pk_bf16_f32)
__device__ __forceinline__ unsigned int f2b2(float a, float b) {
    bf16x2 r = __builtin_amdgcn_cvt_pk_bf16_f32(a, b);
    return *(unsigned int*)&r;
}
#else
__device__ __forceinline__ unsigned int f2b2(float a, float b) {
    return (unsigned int)f2b(a) | ((unsigned int)f2b(b) << 16);
}
#endif

// async global->LDS DMA, 16B per lane; LDS dest = wave-uniform base + lane*16
__device__ __forceinline__ void gload16(const unsigned short* g, unsigned short* l) {
    __builtin_amdgcn_global_load_lds(
        (const __attribute__((address_space(1))) unsigned int*)(g),
        (__attribute__((address_space(3))) unsigned int*)(l),
        16, 0, 0);
}
// 4B per lane variant; LDS dest = base + lane*4
__device__ __forceinline__ void gload4(const int* g, int* l) {
    __builtin_amdgcn_global_load_lds(
        (const __attribute__((address_space(1))) unsigned int*)(g),
        (__attribute__((address_space(3))) unsigned int*)(l),
        4, 0, 0);
}

// ---------------------------------------------------------------------------
// fp32 -> bf16 convert (flat)
// ---------------------------------------------------------------------------
__global__ __launch_bounds__(256) void conv_bf16(const float* __restrict__ s,
                                                 unsigned short* __restrict__ d, int n)
{
    int i = blockIdx.x * blockDim.x + threadIdx.x;
    int stride = gridDim.x * blockDim.x;
    for (int idx = i * 4; idx < n; idx += stride * 4) {
        float4 v = *(const float4*)(s + idx);
        uint2 o;
        o.x = f2b2(v.x, v.y);
        o.y = f2b2(v.z, v.w);
        *(uint2*)(d + idx) = o;
    }
}

// ---------------------------------------------------------------------------
// Fused weight transpose+convert: Wq|Wk|Wv (fp32, [2048][C]) -> bf16 [C][2048]
// ---------------------------------------------------------------------------
__global__ __launch_bounds__(256) void transp_conv_qkv(const float* __restrict__ Wq,
                                                       const float* __restrict__ Wk,
                                                       const float* __restrict__ Wv,
                                                       unsigned short* __restrict__ dst)
{
    __shared__ float t[32][33];
    const int tx = threadIdx.x, ty = threadIdx.y;   // (32,8)
    int bx = blockIdx.x;
    const float* src; int C, cb, dco;
    if (bx < 32)      { src = Wq; C = 1024; cb = bx;      dco = 0; }
    else if (bx < 40) { src = Wk; C = 256;  cb = bx - 32; dco = 1024; }
    else              { src = Wv; C = 256;  cb = bx - 40; dco = 1280; }
    const int c = cb * 32 + tx;
    const int r0 = blockIdx.y * 32;
#pragma unroll
    for (int i = 0; i < 4; ++i)
        t[ty + i * 8][tx] = src[(size_t)(r0 + ty + i * 8) * C + c];
    __syncthreads();
    const int cc = cb * 32 + ty;
#pragma unroll
    for (int i = 0; i < 4; ++i)
        dst[(size_t)(dco + cc + i * 8) * 2048 + r0 + tx] = f2b(t[tx][ty + i * 8]);
}

__global__ __launch_bounds__(256) void transp_conv(const float* __restrict__ src, int R, int C,
                                                   unsigned short* __restrict__ dst, int pitch)
{
    __shared__ float t[32][33];
    const int tx = threadIdx.x, ty = threadIdx.y;
    const int c = blockIdx.x * 32 + tx;
    const int r0 = blockIdx.y * 32;
#pragma unroll
    for (int i = 0; i < 4; ++i)
        t[ty + i * 8][tx] = src[(size_t)(r0 + ty + i * 8) * C + c];
    __syncthreads();
    const int cc = blockIdx.x * 32 + ty;
#pragma unroll
    for (int i = 0; i < 4; ++i)
        dst[(size_t)(cc + i * 8) * pitch + r0 + tx] = f2b(t[tx][ty + i * 8]);
}

// ---------------------------------------------------------------------------
// bf16 MFMA GEMM, B^T input: C[M][N] = A[M][K] @ Bt[N][K]^T
// BM=128, BN=64, BK=64; 256 threads (4 waves, 2x2); double-buffered
// global_load_lds staging; LDS as pitch-32 sub-tiles.  (unchanged from R7)
// ---------------------------------------------------------------------------
template <int MODE>
__global__ __launch_bounds__(256, 3) void gemm_bt_mfma(
    const unsigned short* __restrict__ A,
    const unsigned short* __restrict__ Bt,
    int M, int N, int K,
    float* __restrict__ Cf,
    unsigned short* __restrict__ qh,
    unsigned short* __restrict__ kh,
    unsigned short* __restrict__ vtt)
{
    __shared__ __align__(16) unsigned short As[2][2 * 128 * 32];
    __shared__ __align__(16) unsigned short Bs[2][2 * 64 * 32];

    const int tid = threadIdx.x;
    const int w = tid >> 6, lane = tid & 63, l15 = lane & 15, quad = lane >> 4;
    const int wm = w & 1, wn = w >> 1;
    const int m0 = blockIdx.y * 128, n0 = blockIdx.x * 64;

    f32x4 acc[4][2];
    const f32x4 zero4 = {0.f, 0.f, 0.f, 0.f};
#pragma unroll
    for (int i = 0; i < 4; ++i)
#pragma unroll
        for (int j = 0; j < 2; ++j) acc[i][j] = zero4;

    const int lrow = lane >> 2, lcol = (lane & 3) * 8;
    const unsigned short* AgL = A  + (size_t)(m0 + w * 32 + lrow) * K + lcol;
    const unsigned short* BgL = Bt + (size_t)(n0 + w * 16 + lrow) * K + lcol;

#pragma unroll
    for (int t = 0; t < 4; ++t) {
        const int sub = t >> 1, half = t & 1;
        gload16(AgL + (size_t)(half * 16) * K + sub * 32,
                &As[0][sub * 4096 + (w * 32 + half * 16) * 32]);
    }
#pragma unroll
    for (int kk = 0; kk < 2; ++kk)
        gload16(BgL + kk * 32, &Bs[0][kk * 2048 + (w * 16) * 32]);
    __syncthreads();

    int cb = 0;
    for (int k0 = 0; k0 < K; k0 += 64) {
        if (k0 + 64 < K) {
            const int nb = cb ^ 1;
#pragma unroll
            for (int t = 0; t < 4; ++t) {
                const int sub = t >> 1, half = t & 1;
                gload16(AgL + (size_t)(half * 16) * K + (k0 + 64) + sub * 32,
                        &As[nb][sub * 4096 + (w * 32 + half * 16) * 32]);
            }
#pragma unroll
            for (int kk = 0; kk < 2; ++kk)
                gload16(BgL + (k0 + 64) + kk * 32, &Bs[nb][kk * 2048 + (w * 16) * 32]);
        }

        bf16x8 af[4][2], bf[2][2];
#pragma unroll
        for (int kk = 0; kk < 2; ++kk) {
#pragma unroll
            for (int mt = 0; mt < 4; ++mt)
                af[mt][kk] = *(const bf16x8*)&As[cb][kk * 4096 + (wm * 64 + mt * 16 + l15) * 32 + quad * 8];
#pragma unroll
            for (int nt = 0; nt < 2; ++nt)
                bf[nt][kk] = *(const bf16x8*)&Bs[cb][kk * 2048 + (wn * 32 + nt * 16 + l15) * 32 + quad * 8];
        }
#pragma unroll
        for (int kk = 0; kk < 2; ++kk)
#pragma unroll
            for (int mt = 0; mt < 4; ++mt)
#pragma unroll
                for (int nt = 0; nt < 2; ++nt)
                    acc[mt][nt] = MFMA_BF16(af[mt][kk], bf[nt][kk], acc[mt][nt]);

        __syncthreads();
        cb ^= 1;
    }

    if (MODE == 0) {
#pragma unroll
        for (int mt = 0; mt < 4; ++mt)
#pragma unroll
            for (int nt = 0; nt < 2; ++nt) {
                const int gn = n0 + wn * 32 + nt * 16 + l15;
#pragma unroll
                for (int r = 0; r < 4; ++r) {
                    const int gm = m0 + wm * 64 + mt * 16 + quad * 4 + r;
                    Cf[(size_t)gm * N + gn] = acc[mt][nt][r];
                }
            }
    } else {
        if (n0 < 1024) {            // Q: tanh -> qh[m][n], pitch 1024
#pragma unroll
            for (int mt = 0; mt < 4; ++mt)
#pragma unroll
                for (int nt = 0; nt < 2; ++nt) {
                    const int gn = n0 + wn * 32 + nt * 16 + l15;
#pragma unroll
                    for (int r = 0; r < 4; ++r) {
                        const int gm = m0 + wm * 64 + mt * 16 + quad * 4 + r;
                        qh[(size_t)gm * 1024 + gn] = f2b(tanhf(acc[mt][nt][r]));
                    }
                }
        } else if (n0 < 1280) {     // K: tanh -> kh[m][n-1024], pitch 256
#pragma unroll
            for (int mt = 0; mt < 4; ++mt)
#pragma unroll
                for (int nt = 0; nt < 2; ++nt) {
                    const int gn = n0 + wn * 32 + nt * 16 + l15 - 1024;
#pragma unroll
                    for (int r = 0; r < 4; ++r) {
                        const int gm = m0 + wm * 64 + mt * 16 + quad * 4 + r;
                        kh[(size_t)gm * 256 + gn] = f2b(tanhf(acc[mt][nt][r]));
                    }
                }
        } else {                    // V: sigmoid -> vtt[(b*4+g)*64+v][s]
#pragma unroll
            for (int mt = 0; mt < 4; ++mt)
#pragma unroll
                for (int nt = 0; nt < 2; ++nt) {
                    const int gn = n0 + wn * 32 + nt * 16 + l15 - 1280;
                    const int g = gn >> 6, vv = gn & 63;
                    const int s0 = m0 + wm * 64 + mt * 16 + quad * 4;
                    const int b = s0 >> 11, sl = s0 & 2047;
                    ushort4 pk;
                    unsigned short* pp = (unsigned short*)&pk;
#pragma unroll
                    for (int r = 0; r < 4; ++r) {
                        float sv = 1.0f / (1.0f + __expf(-acc[mt][nt][r]));
                        pp[r] = f2b(sv);
                    }
                    *(ushort4*)&vtt[((size_t)(b * 4 + g) * 64 + vv) * 2048 + sl] = pk;
                }
        }
    }
}

// ---------------------------------------------------------------------------
// MFMA flash attention (R13 = R9 base + softmax-VALU cuts):
// paired q-tiles (uniform 33 k-tiles/block, grid 512), DMA-staged
// double-buffered K/V, fixed-max softmax (|s|<1 -> p=exp2(s*log2e/64)).
// R13a: P bf16 conversion via packed v_cvt_pk_bf16_f32 (8 insts vs ~48).
// R13b: l computed on the MFMA pipe (lacc = P . ones) -> no psum VALU chain,
//       no end-of-half shuffle reduction; l rows align with oacc rows.
// ---------------------------------------------------------------------------
__global__ __launch_bounds__(256) void rosa_attn_mfma(
    const unsigned short* __restrict__ qh,
    const unsigned short* __restrict__ kh,
    const unsigned short* __restrict__ vtt,
    const int* __restrict__ amask,
    const float* __restrict__ emb0,
    const float* __restrict__ emb1,
    unsigned short* __restrict__ ob)
{
    __shared__ __align__(16) unsigned short Ks[2][2][64 * 32];  // [buf][kk][row*32+c]
    __shared__ __align__(16) unsigned short Vs[2][2][64 * 32];  // [buf][kk][v*32+j]
    __shared__ __align__(16) unsigned short Ps[4][16][72];      // [wave][q][j]
    __shared__ int Mski[2][64];

    const int pairI = blockIdx.x;                 // 0..15
    const int h = blockIdx.y, b = blockIdx.z, g = h >> 2;
    const int tid = threadIdx.x;
    const int w = tid >> 6, lane = tid & 63, l15 = lane & 15, quad = lane >> 4;

    // DMA lane geometry: row = lane>>2 (16 rows/issue), col = (lane&3)*8
    const int lrow = lane >> 2, lcol = (lane & 3) * 8;
    const unsigned short* kst = kh + (size_t)b * 2048 * 256 + g * 64
                               + (size_t)(w * 16 + lrow) * 256 + lcol;   // + k0*256 + kk*32
    const unsigned short* vst = vtt + ((size_t)(b * 4 + g) * 64) * 2048
                               + (size_t)(w * 16 + lrow) * 2048 + lcol;  // + k0 + kk*32
    const int* mbase = amask + b * 2048;

    const f32x4 zero4 = {0.f, 0.f, 0.f, 0.f};
    const float cexp = 0.0225421100f;             // log2(e)/64
    const short oneb = (short)0x3F80;             // bf16 1.0
    const bf16x8 ones8 = {oneb, oneb, oneb, oneb, oneb, oneb, oneb, oneb};

#define STAGE_TILE(k0s, buf)                                              \
    {                                                                     \
        gload16(kst + (size_t)(k0s) * 256,      &Ks[buf][0][(w * 16) * 32]); \
        gload16(kst + (size_t)(k0s) * 256 + 32, &Ks[buf][1][(w * 16) * 32]); \
        gload16(vst + (k0s),                    &Vs[buf][0][(w * 16) * 32]); \
        gload16(vst + (k0s) + 32,               &Vs[buf][1][(w * 16) * 32]); \
        if (w == 0) gload4(mbase + (k0s) + lane, &Mski[buf][0]);          \
    }

    for (int half = 0; half < 2; ++half) {
        const int qt = (half == 0) ? pairI : 31 - pairI;
        const int q0 = qt * 64;
        const int nkt = qt + 1;
        const int qg = q0 + w * 16 + l15;

        // Q B-fragment (n = q = l15, k = d), per wave, from global (L2-hot)
        const unsigned short* qrow = qh + ((size_t)(b * 2048 + q0 + w * 16 + l15) * 16 + h) * 64;
        const bf16x8 qf0 = *(const bf16x8*)(qrow + quad * 8);
        const bf16x8 qf1 = *(const bf16x8*)(qrow + 32 + quad * 8);

        f32x4 oacc[4];
#pragma unroll
        for (int t = 0; t < 4; ++t) oacc[t] = zero4;
        f32x4 lacc = zero4;                       // l via MFMA (P . ones)

        __syncthreads();           // protect bufs from previous half's readers
        STAGE_TILE(0, 0)
        __syncthreads();           // vmcnt(0) drain: tile 0 visible

        int cb = 0;
        for (int kt = 0; kt < nkt; ++kt) {
            if (kt + 1 < nkt) STAGE_TILE((kt + 1) * 64, cb ^ 1)

            const int k0 = kt * 64;
            const bool diag = (kt == qt);
            const int ntlim = diag ? (w + 1) : 4;

            // S^T = K.Q^T per 16x16 sub-tile; fixed-max softmax; pack P^T
#pragma unroll
            for (int nt = 0; nt < 4; ++nt) {
                uint2 pk;
                if (nt < ntlim) {
                    bf16x8 kf0 = *(const bf16x8*)&Ks[cb][0][(nt * 16 + l15) * 32 + quad * 8];
                    bf16x8 kf1 = *(const bf16x8*)&Ks[cb][1][(nt * 16 + l15) * 32 + quad * 8];
                    f32x4 sc = MFMA_BF16(kf0, qf0, zero4);
                    sc = MFMA_BF16(kf1, qf1, sc);
                    const int4 m4 = *(const int4*)&Mski[cb][nt * 16 + quad * 4];
                    const int* mm = (const int*)&m4;
                    float p[4];
#pragma unroll
                    for (int r = 0; r < 4; ++r) {
                        float pv = __builtin_exp2f(sc[r] * cexp);
                        bool valid = (mm[r] != 0);
                        if (diag) valid = valid && ((k0 + nt * 16 + quad * 4 + r) <= qg);
                        p[r] = valid ? pv : 0.0f;
                    }
                    pk.x = f2b2(p[0], p[1]);
                    pk.y = f2b2(p[2], p[3]);
                } else {
                    pk.x = 0; pk.y = 0;
                }
                *(uint2*)&Ps[w][l15][nt * 16 + quad * 4] = pk;   // P^T packed along j
            }

            // O += P.V ; l += P.1  (in-wave DS ordering covers Ps write->read)
            const bf16x8 pf0 = *(const bf16x8*)&Ps[w][l15][quad * 8];
            const bf16x8 pf1 = *(const bf16x8*)&Ps[w][l15][32 + quad * 8];
#pragma unroll
            for (int nt = 0; nt < 4; ++nt) {
                bf16x8 vf0 = *(const bf16x8*)&Vs[cb][0][(nt * 16 + l15) * 32 + quad * 8];
                bf16x8 vf1 = *(const bf16x8*)&Vs[cb][1][(nt * 16 + l15) * 32 + quad * 8];
                oacc[nt] = MFMA_BF16(pf0, vf0, oacc[nt]);
                oacc[nt] = MFMA_BF16(pf1, vf1, oacc[nt]);
            }
            lacc = MFMA_BF16(pf0, ones8, lacc);
            lacc = MFMA_BF16(pf1, ones8, lacc);

            if (kt + 1 < nkt) {
                __syncthreads();   // drains next tile's DMA + all waves' cb reads
                cb ^= 1;
            }
        }

        // epilogue: oacc/lacc rows = q_local = quad*4+r, col = v = nt*16+l15
        float invl[4];
#pragma unroll
        for (int r = 0; r < 4; ++r) invl[r] = 1.0f / lacc[r];
#pragma unroll
        for (int nt = 0; nt < 4; ++nt) {
            const float e0 = emb0[h * 64 + nt * 16 + l15];
            const float e1 = emb1[h * 64 + nt * 16 + l15];
#pragma unroll
            for (int r = 0; r < 4; ++r) {
                const float ctx = oacc[nt][r] * invl[r];
                const float val = e0 + ctx * (e1 - e0);
                const size_t s_idx = (size_t)(b * 2048 + q0 + w * 16 + quad * 4 + r);
                ob[(s_idx * 16 + h) * 64 + nt * 16 + l15] = f2b(val);
            }
        }
    }
#undef STAGE_TILE
}

// ---------------------------------------------------------------------------
extern "C" void kernel_launch(void* const* d_in, const int* in_sizes, int n_in,
                              void* d_out, int out_size, void* d_ws, size_t ws_size,
                              hipStream_t stream)
{
    const float* x    = (const float*)d_in[0];
    const int*   amask= (const int*)d_in[1];
    const float* Wq   = (const float*)d_in[2];
    const float* Wk   = (const float*)d_in[3];
    const float* Wv   = (const float*)d_in[4];
    const float* Wo   = (const float*)d_in[5];
    const float* emb0 = (const float*)d_in[6];
    const float* emb1 = (const float*)d_in[7];
    float* out = (float*)d_out;

    char* base = (char*)d_ws;
    unsigned short* xh    = (unsigned short*)(base);                      // 16 MB
    unsigned short* ob    = xh;                                           // aliases xh
    unsigned short* Wqkvt = (unsigned short*)(base + (16u << 20));        // 6 MB
    unsigned short* Wot   = (unsigned short*)(base + (22u << 20));        // 4 MB
    unsigned short* qh    = (unsigned short*)(base + (26u << 20));        // 8 MB
    unsigned short* kh    = (unsigned short*)(base + (34u << 20));        // 2 MB
    unsigned short* vtt   = (unsigned short*)(base + (36u << 20));        // 2 MB

    conv_bf16<<<2048, 256, 0, stream>>>(x, xh, 4096 * 2048);
    transp_conv_qkv<<<dim3(48, 64), dim3(32, 8), 0, stream>>>(Wq, Wk, Wv, Wqkvt);
    transp_conv<<<dim3(64, 32), dim3(32, 8), 0, stream>>>(Wo, 1024, 2048, Wot, 1024);

    gemm_bt_mfma<1><<<dim3(24, 32), 256, 0, stream>>>(xh, Wqkvt, 4096, 1536, 2048,
                                                      nullptr, qh, kh, vtt);
    rosa_attn_mfma<<<dim3(16, 16, 2), 256, 0, stream>>>(qh, kh, vtt, amask, emb0, emb1, ob);
    gemm_bt_mfma<0><<<dim3(32, 32), 256, 0, stream>>>(ob, Wot, 4096, 2048, 1024,
                                                      out, nullptr, nullptr, nullptr);
}